// Round 1
// 300.636 us; speedup vs baseline: 1.1221x; 1.1221x over previous
//
#include <hip/hip_runtime.h>
#include <hip/hip_bf16.h>
#include <math.h>

// Problem constants (B=4, L=1024, D=A=1024, H=16, DH=64)
#define BB 4
#define LL 1024
#define DD 1024
#define AA 1024
#define HH 16
#define DHH 64
#define LOG2E 1.44269504f
#define QSC 0.045084223f        /* (1/32) * log2(e) */
#define MBIAS -144269.5f        /* -100000 * log2(e) */

typedef __attribute__((ext_vector_type(8))) short short8;
typedef __attribute__((ext_vector_type(4))) float floatx4;

__device__ __forceinline__ float bf2f(unsigned short u) {
    union { unsigned u; float f; } x; x.u = ((unsigned)u) << 16; return x.f;
}
__device__ __forceinline__ unsigned short f2bf(float f) {
    union { float f; unsigned u; } x; x.f = f;
    unsigned r = x.u + 0x7fffu + ((x.u >> 16) & 1u); // RNE
    return (unsigned short)(r >> 16);
}
__device__ __forceinline__ unsigned pkbf(float a, float b) { // packed RNE pair
    union { __hip_bfloat162 h; unsigned u; } c;
    c.h = __float22bfloat162_rn(make_float2(a, b));
    return c.u;
}

// ---------------------------------------------------------------------------
// fp32 -> bf16 bulk converter. Unit = 1M elems = 1024 blocks; block = 1024 elems.
// ---------------------------------------------------------------------------
struct ConvDesc { const float* s[12]; unsigned short* d[12]; };

__global__ __launch_bounds__(256) void conv_f2b(ConvDesc cd) {
    const int u  = blockIdx.x >> 10;
    const int lb = blockIdx.x & 1023;
    const int idx = lb * 1024 + threadIdx.x * 4;
    float4 v = *reinterpret_cast<const float4*>(cd.s[u] + idx);
    uint2 o;
    o.x = pkbf(v.x, v.y);
    o.y = pkbf(v.z, v.w);
    *reinterpret_cast<uint2*>(cd.d[u] + idx) = o;
}

// Stage 8 k-elements into LDS: fp32 (32B load + packed convert) or bf16 (16B copy).
template <bool F32>
__device__ __forceinline__ void stage8(unsigned short* dst, const void* src, size_t off) {
    if (F32) {
        const float* s = (const float*)src + off;
        float4 a = ((const float4*)s)[0];
        float4 b = ((const float4*)s)[1];
        uint4 t;
        t.x = pkbf(a.x, a.y); t.y = pkbf(a.z, a.w);
        t.z = pkbf(b.x, b.y); t.w = pkbf(b.z, b.w);
        *reinterpret_cast<uint4*>(dst) = t;
    } else {
        *reinterpret_cast<uint4*>(dst) =
            *reinterpret_cast<const uint4*>((const unsigned short*)src + off);
    }
}

// ---------------------------------------------------------------------------
// 128x64-tile MFMA GEMM core. C[m][n] = sum_k A[m][k]*B[n][k] (+2nd pair).
// 4 waves (2x2): wave computes 64x32 = 4x2 frags of 16x16. BK=32.
// grid: x = N/64 (=16), y = M/128 (=32).
// ---------------------------------------------------------------------------
template <int NPAIR, bool A_F32, bool B_F32>
__device__ __forceinline__ void gemm_core(const void* A0, const void* B0,
                                          const void* A1, const void* B1,
                                          unsigned short As[128][40],
                                          unsigned short Bs[64][40],
                                          floatx4 (&acc)[4][2])
{
    const int tid  = threadIdx.x;
    const int lane = tid & 63;
    const int l16  = lane & 15;
    const int quad = lane >> 4;
    const int wave = tid >> 6;
    const int wm = wave >> 1, wn = wave & 1;
    const int mblk = blockIdx.y * 128;
    const int nblk = blockIdx.x * 64;
    const int srow = tid >> 2;        // 0..63
    const int scol = (tid & 3) << 3;  // 0,8,16,24

    for (int pair = 0; pair < NPAIR; ++pair) {
        const void* Ap = pair ? A1 : A0;
        const void* Bp = pair ? B1 : B0;
        for (int k0 = 0; k0 < DD; k0 += 32) {
            __syncthreads();
            stage8<A_F32>(&As[srow][scol],      Ap, (size_t)(mblk + srow) * DD + k0 + scol);
            stage8<A_F32>(&As[srow + 64][scol], Ap, (size_t)(mblk + srow + 64) * DD + k0 + scol);
            stage8<B_F32>(&Bs[srow][scol],      Bp, (size_t)(nblk + srow) * DD + k0 + scol);
            __syncthreads();
            short8 af[4], bfr[2];
            for (int i = 0; i < 4; ++i)
                af[i] = *reinterpret_cast<const short8*>(&As[wm * 64 + i * 16 + l16][quad * 8]);
            for (int j = 0; j < 2; ++j)
                bfr[j] = *reinterpret_cast<const short8*>(&Bs[wn * 32 + j * 16 + l16][quad * 8]);
            for (int i = 0; i < 4; ++i)
                for (int j = 0; j < 2; ++j)
                    acc[i][j] = __builtin_amdgcn_mfma_f32_16x16x32_bf16(af[i], bfr[j], acc[i][j], 0, 0, 0);
        }
    }
}

__device__ __forceinline__ void store_nat(floatx4 (&acc)[4][2], unsigned short* C) {
    const int lane = threadIdx.x & 63;
    const int l16  = lane & 15;
    const int quad = lane >> 4;
    const int wave = threadIdx.x >> 6;
    const int wm = wave >> 1, wn = wave & 1;
    for (int i = 0; i < 4; ++i)
        for (int j = 0; j < 2; ++j) {
            const int mg0 = blockIdx.y * 128 + wm * 64 + i * 16 + quad * 4; // row=quad*4+r
            const int ng  = blockIdx.x * 64 + wn * 32 + j * 16 + l16;       // col=l16
            for (int r = 0; r < 4; ++r)
                C[(size_t)(mg0 + r) * AA + ng] = f2bf(acc[i][j][r]);
        }
}

__device__ __forceinline__ void store_vt(floatx4 (&acc)[4][2], unsigned short* vt) {
    const int lane = threadIdx.x & 63;
    const int l16  = lane & 15;
    const int quad = lane >> 4;
    const int wave = threadIdx.x >> 6;
    const int wm = wave >> 1, wn = wave & 1;
    for (int i = 0; i < 4; ++i)
        for (int j = 0; j < 2; ++j) {
            const int mg0 = blockIdx.y * 128 + wm * 64 + i * 16 + quad * 4;
            const int ng  = blockIdx.x * 64 + wn * 32 + j * 16 + l16;
            // vt[((b*H+h)*DH+dh)*L + l]: 4 acc rows are consecutive l -> one 8B store
            const int h = ng >> 6, dh = ng & 63;
            const int b = mg0 >> 10, l = mg0 & 1023;
            ushort4 pv;
            pv.x = f2bf(acc[i][j][0]); pv.y = f2bf(acc[i][j][1]);
            pv.z = f2bf(acc[i][j][2]); pv.w = f2bf(acc[i][j][3]);
            *reinterpret_cast<ushort4*>(&vt[((size_t)((b * HH + h) * DHH + dh)) * LL + l]) = pv;
        }
}

template <int NPAIR, bool A_F32, bool B_F32>
__global__ __launch_bounds__(256) void gemm_nat(const void* __restrict__ A0,
                                                const void* __restrict__ B0,
                                                const void* __restrict__ A1,
                                                const void* __restrict__ B1,
                                                unsigned short* __restrict__ Cout)
{
    __shared__ alignas(16) unsigned short As[128][40];
    __shared__ alignas(16) unsigned short Bs[64][40];
    floatx4 acc[4][2] = {};
    gemm_core<NPAIR, A_F32, B_F32>(A0, B0, A1, B1, As, Bs, acc);
    store_nat(acc, Cout);
}

// K and V projections fused over gridDim.z (different B + store layout).
template <bool A_F32>
__global__ __launch_bounds__(256) void gemm_kv(const void* __restrict__ x,
                                               const void* __restrict__ Wk,
                                               const void* __restrict__ Wv,
                                               unsigned short* __restrict__ kk,
                                               unsigned short* __restrict__ vt)
{
    __shared__ alignas(16) unsigned short As[128][40];
    __shared__ alignas(16) unsigned short Bs[64][40];
    floatx4 acc[4][2] = {};
    if (blockIdx.z == 0) {
        gemm_core<1, A_F32, false>(x, Wk, nullptr, nullptr, As, Bs, acc);
        store_nat(acc, kk);
    } else {
        gemm_core<1, A_F32, false>(x, Wv, nullptr, nullptr, As, Bs, acc);
        store_vt(acc, vt);
    }
}

// ---------------------------------------------------------------------------
// Flash attention WITHOUT online softmax (scores bounded, see prev version).
// v2: K/V tiles staged in LDS once per block (shared by 4 waves) instead of
// each wave pulling the full 8KB K + 8KB V tile from L2 every iteration
// (4x cache-traffic cut). XOR-swizzled LDS layout (byte ^= (row&7)<<4) makes
// ds_read_b128 fragment reads conflict-free. Next tile's global loads are
// issued before compute (T14 async-split) so L2/HBM latency hides under the
// MFMA+exp2 phase. Mask bias precomputed to LDS. Blocks decoded so all 16
// q-tiles of one (b,h) land on one XCD (blk&7 = XCD under round-robin).
// ao aliases qc safely (Q read first, ao written last, same region per block).
// ---------------------------------------------------------------------------
__device__ __forceinline__ int swzb(int row, int slot) {
    // byte offset into a 64-row x 128B tile, slot = 16B column, XOR-swizzled
    return (row << 7) + ((slot ^ (row & 7)) << 4);
}

__global__ __launch_bounds__(256) void attn_flash(const unsigned short* qc,
                                                  const unsigned short* __restrict__ kmat,
                                                  const unsigned short* __restrict__ vt,
                                                  const int* __restrict__ mask,
                                                  unsigned short* ao)
{
    const int blk = blockIdx.x;
    // XCD-grouped decode: blk&7 = XCD (round-robin dispatch); give each XCD
    // 8 whole (b,h) groups so K/V stay L2-resident per XCD.
    const int xcd = blk & 7;
    const int sub = blk >> 3;          // 0..127
    const int bh  = xcd * 8 + (sub >> 4);
    const int qt  = sub & 15;
    const int b   = bh >> 4;
    const int h   = bh & 15;

    const int wave = threadIdx.x >> 6;
    const int lane = threadIdx.x & 63;
    const int l16  = lane & 15;
    const int quad = lane >> 4;
    const int q0 = qt * 64 + wave * 16;

    __shared__ alignas(16) unsigned short Ks[64 * 64];   // swizzled [k][dh]  8KB
    __shared__ alignas(16) unsigned short Vs[64 * 64];   // swizzled [dh][k]  8KB
    __shared__ alignas(16) unsigned short Plds[4][16][72]; // per-wave P tile 9KB
    __shared__ float Ml[LL];                              // mask bias        4KB
    char* Ksb = (char*)Ks;
    char* Vsb = (char*)Vs;

    // mask bias precompute (cols for this batch row)
    const int* bm = mask + b * LL;
    for (int i = 0; i < 4; ++i) {
        const int c = threadIdx.x + i * 256;
        Ml[c] = (1.0f - (float)bm[c]) * MBIAS;
    }

    // Q fragments (dh 0..31, 32..63), scaled by SCALE*log2e
    short8 aq[2];
    for (int s = 0; s < 2; ++s) {
        const unsigned short* p =
            qc + (size_t)(b * LL + q0 + l16) * AA + h * DHH + s * 32 + quad * 8;
        short8 t = *reinterpret_cast<const short8*>(p);
        for (int e = 0; e < 8; ++e)
            t[e] = (short)f2bf(bf2f((unsigned short)t[e]) * QSC);
        aq[s] = t;
    }

    floatx4 O[4] = {};
    float lp[4] = {0.f, 0.f, 0.f, 0.f};

    // prologue: load tile kb=0 into regs (lane c covers row c>>3, 16B slot c&7)
    uint4 kr[2], vr[2];
    {
        const unsigned short* kbase = kmat + (size_t)(b * LL) * AA + h * DHH;
        const unsigned short* vbase = vt + (size_t)((b * HH + h) * DHH) * LL;
        for (int i = 0; i < 2; ++i) {
            const int c = threadIdx.x + (i << 8);
            const int row = c >> 3, slot = c & 7;
            kr[i] = *reinterpret_cast<const uint4*>(kbase + (size_t)row * AA + slot * 8);
            vr[i] = *reinterpret_cast<const uint4*>(vbase + (size_t)row * LL + slot * 8);
        }
    }

    for (int kb = 0; kb < LL; kb += 64) {
        __syncthreads();                       // prev tile's compute done
        for (int i = 0; i < 2; ++i) {          // regs -> swizzled LDS
            const int c = threadIdx.x + (i << 8);
            const int row = c >> 3, slot = c & 7;
            *reinterpret_cast<uint4*>(Ksb + swzb(row, slot)) = kr[i];
            *reinterpret_cast<uint4*>(Vsb + swzb(row, slot)) = vr[i];
        }
        __syncthreads();                       // tile visible
        if (kb + 64 < LL) {                    // prefetch next tile (hides latency)
            const unsigned short* kbase = kmat + (size_t)(b * LL + kb + 64) * AA + h * DHH;
            const unsigned short* vbase = vt + (size_t)((b * HH + h) * DHH) * LL + kb + 64;
            for (int i = 0; i < 2; ++i) {
                const int c = threadIdx.x + (i << 8);
                const int row = c >> 3, slot = c & 7;
                kr[i] = *reinterpret_cast<const uint4*>(kbase + (size_t)row * AA + slot * 8);
                vr[i] = *reinterpret_cast<const uint4*>(vbase + (size_t)row * LL + slot * 8);
            }
        }

        floatx4 S[4];
        for (int j = 0; j < 4; ++j) {
            const int rr = j * 16 + l16;
            const short8 kf0 = *reinterpret_cast<const short8*>(Ksb + swzb(rr, quad));
            const short8 kf1 = *reinterpret_cast<const short8*>(Ksb + swzb(rr, quad + 4));
            const float madd = Ml[kb + rr];    // mask bias rides in C-init
            floatx4 s_ = {madd, madd, madd, madd};
            s_ = __builtin_amdgcn_mfma_f32_16x16x32_bf16(aq[0], kf0, s_, 0, 0, 0);
            s_ = __builtin_amdgcn_mfma_f32_16x16x32_bf16(aq[1], kf1, s_, 0, 0, 0);
            S[j] = s_;
        }
        for (int j = 0; j < 4; ++j)
            for (int r = 0; r < 4; ++r) {
                S[j][r] = exp2f(S[j][r]);
                lp[r] += S[j][r];
            }
        // P: C-layout -> per-wave LDS -> A-layout
        for (int j = 0; j < 4; ++j)
            for (int r = 0; r < 4; ++r)
                Plds[wave][quad * 4 + r][j * 16 + l16] = f2bf(S[j][r]);
        __asm__ volatile("s_waitcnt lgkmcnt(0)" ::: "memory");
        const short8 ap0 = *reinterpret_cast<const short8*>(&Plds[wave][l16][quad * 8]);
        const short8 ap1 = *reinterpret_cast<const short8*>(&Plds[wave][l16][32 + quad * 8]);
        for (int t = 0; t < 4; ++t) {
            const int rr = t * 16 + l16;
            const short8 bv0 = *reinterpret_cast<const short8*>(Vsb + swzb(rr, quad));
            const short8 bv1 = *reinterpret_cast<const short8*>(Vsb + swzb(rr, quad + 4));
            O[t] = __builtin_amdgcn_mfma_f32_16x16x32_bf16(ap0, bv0, O[t], 0, 0, 0);
            O[t] = __builtin_amdgcn_mfma_f32_16x16x32_bf16(ap1, bv1, O[t], 0, 0, 0);
        }
    }
    float linv[4];
    for (int r = 0; r < 4; ++r) {
        float s = lp[r];
        s += __shfl_xor(s, 1);
        s += __shfl_xor(s, 2);
        s += __shfl_xor(s, 4);
        s += __shfl_xor(s, 8);
        linv[r] = 1.0f / s;
    }
    for (int t = 0; t < 4; ++t)
        for (int r = 0; r < 4; ++r)
            ao[(size_t)(b * LL + q0 + quad * 4 + r) * AA + h * DHH + t * 16 + l16] =
                f2bf(O[t][r] * linv[r]);
}

// bias + LayerNorm per 1024-row. Input bf16 scratch; params fp32; output FP32.
__global__ __launch_bounds__(256) void ln_f32(const unsigned short* __restrict__ X,
                                              const float* __restrict__ bo,
                                              const float* __restrict__ gamma,
                                              const float* __restrict__ beta,
                                              float* __restrict__ out)
{
    const int row = blockIdx.x;
    const unsigned short* x = X + (size_t)row * AA;
    float v[4];
    float s = 0.f, s2 = 0.f;
    for (int e = 0; e < 4; ++e) {
        const int c = threadIdx.x + e * 256;
        const float f = bf2f(x[c]) + bo[c];
        v[e] = f; s += f; s2 += f * f;
    }
    for (int d = 1; d < 64; d <<= 1) { s += __shfl_xor(s, d); s2 += __shfl_xor(s2, d); }
    __shared__ float red[4][2];
    const int wave = threadIdx.x >> 6;
    const int lane = threadIdx.x & 63;
    if (lane == 0) { red[wave][0] = s; red[wave][1] = s2; }
    __syncthreads();
    s  = red[0][0] + red[1][0] + red[2][0] + red[3][0];
    s2 = red[0][1] + red[1][1] + red[2][1] + red[3][1];
    const float mean = s * (1.0f / AA);
    const float var  = s2 * (1.0f / AA) - mean * mean;
    const float rstd = rsqrtf(var + 1e-5f);
    for (int e = 0; e < 4; ++e) {
        const int c = threadIdx.x + e * 256;
        out[(size_t)row * AA + c] = (v[e] - mean) * rstd * gamma[c] + beta[c];
    }
}

extern "C" void kernel_launch(void* const* d_in, const int* in_sizes, int n_in,
                              void* d_out, int out_size, void* d_ws, size_t ws_size,
                              hipStream_t stream)
{
    const float* x     = (const float*)d_in[0];  // fp32 [B][L][D]
    const float* qrs   = (const float*)d_in[1];
    const float* Wk    = (const float*)d_in[2];  // fp32 [A][D]
    const float* Wqs   = (const float*)d_in[3];
    const float* Wqo   = (const float*)d_in[4];
    const float* Wv    = (const float*)d_in[5];
    const void*  Wo    = d_in[6];
    const float* bo    = (const float*)d_in[7];
    const float* gamma = (const float*)d_in[8];
    const float* beta  = (const float*)d_in[9];
    const int*   mask  = (const int*)d_in[10];

    // Scratch plan:
    //   ws[0,8):   qc (q_comb out; attn overwrites own region)     [always]
    //   ws[8,16):  kk; later pj (Wo out)                           [always]
    //   ws[16,24): xb  (x as bf16)            [only if ws_size >= 32 MiB]
    //   ws[24,32): qb  (queries as bf16)      [only if ws_size >= 32 MiB]
    //   d_out[0,8):  vt (dead after attn)
    //   d_out[8,16): Wqs_b,Wqo_b,Wk_b,Wv_b (2 MiB each; dead after projections)
    //   d_out[0,16): final fp32 (written last)
    char* ws = (char*)d_ws;
    unsigned short* qc = (unsigned short*)(ws + (size_t)0);
    unsigned short* kk = (unsigned short*)(ws + ((size_t)8 << 20));
    unsigned short* xb = (unsigned short*)(ws + ((size_t)16 << 20));
    unsigned short* qb = (unsigned short*)(ws + ((size_t)24 << 20));
    unsigned short* vt = (unsigned short*)d_out;
    unsigned short* Wb = (unsigned short*)((char*)d_out + ((size_t)8 << 20));
    unsigned short* Wqs_b = Wb;                 // 1M elems each
    unsigned short* Wqo_b = Wb + (1u << 20);
    unsigned short* Wk_b  = Wb + (2u << 20);
    unsigned short* Wv_b  = Wb + (3u << 20);
    unsigned short* ao = qc;
    unsigned short* pj = kk;

    const bool full = ws_size >= ((size_t)32 << 20);
    ConvDesc cd;
    int nu = 0;
    if (full) {
        for (int i = 0; i < 4; ++i) { cd.s[nu] = x   + (size_t)i * (1u << 20); cd.d[nu] = xb + (size_t)i * (1u << 20); ++nu; }
        for (int i = 0; i < 4; ++i) { cd.s[nu] = qrs + (size_t)i * (1u << 20); cd.d[nu] = qb + (size_t)i * (1u << 20); ++nu; }
    }
    cd.s[nu] = Wqs; cd.d[nu] = Wqs_b; ++nu;
    cd.s[nu] = Wqo; cd.d[nu] = Wqo_b; ++nu;
    cd.s[nu] = Wk;  cd.d[nu] = Wk_b;  ++nu;
    cd.s[nu] = Wv;  cd.d[nu] = Wv_b;  ++nu;
    conv_f2b<<<nu * 1024, 256, 0, stream>>>(cd);

    dim3 g(AA / 64, (BB * LL) / 128);
    dim3 gkv(AA / 64, (BB * LL) / 128, 2);
    if (full) {
        gemm_nat<2, false, false><<<g, 256, 0, stream>>>(xb, Wqs_b, qb, Wqo_b, qc);
        gemm_kv<false><<<gkv, 256, 0, stream>>>(xb, Wk_b, Wv_b, kk, vt);
    } else {
        gemm_nat<2, true, false><<<g, 256, 0, stream>>>(x, Wqs_b, qrs, Wqo_b, qc);
        gemm_kv<true><<<gkv, 256, 0, stream>>>(x, Wk_b, Wv_b, kk, vt);
    }
    attn_flash<<<BB * HH * (LL / 64), 256, 0, stream>>>(qc, kk, vt, mask, ao);
    gemm_nat<1, false, true><<<g, 256, 0, stream>>>(ao, Wo, nullptr, nullptr, pj);
    ln_f32<<<BB * LL, 256, 0, stream>>>(pj, bo, gamma, beta, (float*)d_out);
}